// Round 1
// baseline (1407.504 us; speedup 1.0000x reference)
//
#include <hip/hip_runtime.h>

// SparseBottleneck: feats(800k,64) -> BN-MLP + submanifold 3x3 conv + BN + residual, out (800k,256) f32.
// Strategy: all BN biases cancel; layer-1/shortcut/layer-3 BN stats computed analytically from
// Gram matrices (G=F^T F, H=h2^T h2); intermediates bf16; all GEMMs via mfma_f32_16x16x32_bf16.

#define NPTS 800000
#define EPSV 1e-5f

typedef __bf16 bf16_t;
typedef __bf16 bf16x8 __attribute__((ext_vector_type(8)));
typedef float f32x4 __attribute__((ext_vector_type(4)));

static __device__ __forceinline__ f32x4 mfma16(bf16x8 a, bf16x8 b, f32x4 c) {
  return __builtin_amdgcn_mfma_f32_16x16x32_bf16(a, b, c, 0, 0, 0);
}
static __device__ __forceinline__ bf16x8 bzero8() {
  bf16x8 z;
#pragma unroll
  for (int i = 0; i < 8; i++) z[i] = (bf16_t)0.0f;
  return z;
}

// ---------------------------------------------------------------------------
// k_prep: convert w1/w2/w3/ws (f32, [k][n] row-major) into frag-swizzled bf16
// arrays: frag f=(ct*2+ks), lane l, elem j  <-  W[ks*32+(l>>4)*8+j][ct*16+(l&15)]
// so each lane's 16B B-fragment is contiguous (ds_read_b128, conflict-free).
__global__ __launch_bounds__(256) void k_prep(
    const float* __restrict__ w1, const float* __restrict__ w2,
    const float* __restrict__ w3, const float* __restrict__ ws,
    bf16_t* __restrict__ w1F, bf16_t* __restrict__ w2F,
    bf16_t* __restrict__ w3F, bf16_t* __restrict__ wsF) {
  int t = blockIdx.x * 256 + threadIdx.x;
  const float* W;
  bf16_t* F;
  int Nc, u;
  if (t < 512) { W = w1; F = w1F; Nc = 64; u = t; }
  else if (t < 5120) {
    int v = t - 512; int grp = v >> 9; u = v & 511;
    W = w2 + grp * 4096; F = w2F + grp * 4096; Nc = 64;
  } else if (t < 7168) { u = t - 5120; W = w3; F = w3F; Nc = 256; }
  else if (t < 9216) { u = t - 7168; W = ws; F = wsF; Nc = 256; }
  else return;
  const int fidx = u >> 6, lane = u & 63;
  const int ct = fidx >> 1, ks = fidx & 1;
  const int n = ct * 16 + (lane & 15);
  const int k0 = ks * 32 + (lane >> 4) * 8;
  bf16_t* dst = F + (size_t)(fidx * 64 + lane) * 8;
#pragma unroll
  for (int j = 0; j < 8; j++) dst[j] = (bf16_t)W[(k0 + j) * Nc + n];
}

// ---------------------------------------------------------------------------
// k_moments: stream rows; (MODE 0) f32 in -> bf16 out (feats->fb);
// (MODE 1) bf16 in, apply relu(a*x+c) -> bf16 out (z2->h2).
// Accumulates Gram (64x64, MFMA syrk on LDS tile) + column sums, atomics at end.
template <int MODE>
__global__ __launch_bounds__(256) void k_moments(
    const void* __restrict__ inp, bf16_t* __restrict__ outb,
    const float* __restrict__ aff_a, const float* __restrict__ aff_c,
    float* __restrict__ Gout, float* __restrict__ colout, int nchunks) {
  __shared__ __align__(16) bf16_t tile[32 * 64];
  __shared__ float lcol[64];
  const int tid = threadIdx.x;
  const int wave = tid >> 6, lane = tid & 63;
  const int row = tid >> 3, c0 = (tid & 7) * 8;

  float aa[8], cc[8];
  if (MODE == 1) {
#pragma unroll
    for (int j = 0; j < 8; j++) { aa[j] = aff_a[c0 + j]; cc[j] = aff_c[c0 + j]; }
  }
  const f32x4 fz = {0.f, 0.f, 0.f, 0.f};
  f32x4 acc[4] = {fz, fz, fz, fz};
  float colacc[8] = {0, 0, 0, 0, 0, 0, 0, 0};
  if (tid < 64) lcol[tid] = 0.f;

  const int am = wave * 16 + (lane & 15);
  const int ak = (lane >> 4) * 8;

  for (int ch = blockIdx.x; ch < nchunks; ch += gridDim.x) {
    const int r0 = ch * 32;
    float v[8];
    if (MODE == 0) {
      const float* p = (const float*)inp + (size_t)(r0 + row) * 64 + c0;
#pragma unroll
      for (int j = 0; j < 8; j++) v[j] = p[j];
    } else {
      const bf16_t* p = (const bf16_t*)inp + (size_t)(r0 + row) * 64 + c0;
#pragma unroll
      for (int j = 0; j < 8; j++) v[j] = fmaxf(aa[j] * (float)p[j] + cc[j], 0.f);
    }
    bf16x8 vb;
#pragma unroll
    for (int j = 0; j < 8; j++) {
      vb[j] = (bf16_t)v[j];
      colacc[j] += (float)vb[j];  // stats on the rounded values actually used downstream
    }
    *(bf16x8*)(&tile[row * 64 + c0]) = vb;
    *(bf16x8*)(&outb[(size_t)(r0 + row) * 64 + c0]) = vb;
    __syncthreads();
    bf16x8 af, bfv;
#pragma unroll
    for (int j = 0; j < 8; j++) af[j] = tile[(ak + j) * 64 + am];
#pragma unroll
    for (int nt = 0; nt < 4; nt++) {
      const int bn = nt * 16 + (lane & 15);
#pragma unroll
      for (int j = 0; j < 8; j++) bfv[j] = tile[(ak + j) * 64 + bn];
      acc[nt] = mfma16(af, bfv, acc[nt]);
    }
    __syncthreads();
  }
#pragma unroll
  for (int j = 0; j < 8; j++) atomicAdd(&lcol[c0 + j], colacc[j]);
  __syncthreads();
  if (tid < 64) atomicAdd(&colout[tid], lcol[tid]);
#pragma unroll
  for (int nt = 0; nt < 4; nt++)
#pragma unroll
    for (int r = 0; r < 4; r++)
      atomicAdd(&Gout[(wave * 16 + (lane >> 4) * 4 + r) * 64 + nt * 16 + (lane & 15)],
                acc[nt][r]);
}

// ---------------------------------------------------------------------------
// k_stats: analytic BN coeffs for z = F@W (+bias, which cancels):
// mean_c = (colsum . W[:,c])/N ; E2_c = W[:,c]^T (G/N) W[:,c]
// a = g*rsqrt(var+eps) ; c = be - a*mean.  One block (1 wave) per channel.
__global__ __launch_bounds__(64) void k_stats(
    const float* __restrict__ G, const float* __restrict__ col,
    const float* __restrict__ W, int stride,
    const float* __restrict__ g, const float* __restrict__ be,
    float* __restrict__ A, float* __restrict__ C) {
  const int c = blockIdx.x, j = threadIdx.x;
  __shared__ float wcol[64];
  float wj = W[j * stride + c];
  wcol[j] = wj;
  __syncthreads();
  float inner = 0.f;
  for (int k = 0; k < 64; k++) inner = fmaf(G[j * 64 + k], wcol[k], inner);
  float e2p = wj * inner;
  float mp = col[j] * wj;
  for (int off = 32; off; off >>= 1) {
    e2p += __shfl_down(e2p, off, 64);
    mp += __shfl_down(mp, off, 64);
  }
  if (j == 0) {
    const float invN = 1.f / (float)NPTS;
    float mean = mp * invN;
    float var = e2p * invN - mean * mean;
    float s = g[c] * rsqrtf(var + EPSV);
    A[c] = s;
    C[c] = be[c] - s * mean;
  }
}

// Moment-based BN coeffs for layer 2 (direct sum/sumsq).
__global__ void k_stats2(const float* __restrict__ sum, const float* __restrict__ ssq,
                         const float* __restrict__ g2, const float* __restrict__ be2,
                         float* __restrict__ a2, float* __restrict__ c2) {
  int c = threadIdx.x;
  if (c >= 64) return;
  const float invN = 1.f / (float)NPTS;
  float mean = sum[c] * invN;
  float var = ssq[c] * invN - mean * mean;
  float s = g2[c] * rsqrtf(var + EPSV);
  a2[c] = s;
  c2[c] = be2[c] - s * mean;
}

// ---------------------------------------------------------------------------
// k1: h1 = relu(a1*(fb@w1)+c1), bf16 out. 1 wave per 16 rows.
__global__ __launch_bounds__(256) void k1_h1(
    const bf16_t* __restrict__ fb, const bf16_t* __restrict__ w1F,
    const float* __restrict__ a1, const float* __restrict__ c1,
    bf16_t* __restrict__ h1) {
  __shared__ __align__(16) bf16_t wl[4096];
  const int tid = threadIdx.x, wave = tid >> 6, lane = tid & 63;
  {
    const float4* s = (const float4*)w1F;
    float4* d = (float4*)wl;
    d[tid] = s[tid];
    d[tid + 256] = s[tid + 256];
  }
  __syncthreads();
  const int r0 = (blockIdx.x * 4 + wave) * 16;
  const int m = lane & 15, q = lane >> 4;
  const bf16x8* fv = (const bf16x8*)(fb + (size_t)r0 * 64);
  bf16x8 a0 = fv[m * 8 + q];
  bf16x8 a1f = fv[m * 8 + 4 + q];
  const bf16x8* wf = (const bf16x8*)wl;
#pragma unroll
  for (int ct = 0; ct < 4; ct++) {
    f32x4 acc = {0.f, 0.f, 0.f, 0.f};
    acc = mfma16(a0, wf[(ct * 2 + 0) * 64 + lane], acc);
    acc = mfma16(a1f, wf[(ct * 2 + 1) * 64 + lane], acc);
    const int col = ct * 16 + m;
    const float A = a1[col], C = c1[col];
#pragma unroll
    for (int r = 0; r < 4; r++)
      h1[(size_t)(r0 + q * 4 + r) * 64 + col] = (bf16_t)fmaxf(A * acc[r] + C, 0.f);
  }
}

// ---------------------------------------------------------------------------
// k2: z2 = sum_k gather(h1, nbr[:,k]) @ w2[k]  (raw, bias cancels); bf16 out.
// Also accumulates per-channel sum/sumsq (block-reduced, then global atomics).
__global__ __launch_bounds__(256) void k2_conv(
    const bf16_t* __restrict__ h1, const int* __restrict__ nbr,
    const bf16_t* __restrict__ w2F, bf16_t* __restrict__ z2,
    float* __restrict__ sum2, float* __restrict__ ssq2, int n_rowtiles) {
  __shared__ __align__(16) bf16_t wl[36864];  // 72KB
  __shared__ float lsum[64], lssq[64];
  const int tid = threadIdx.x, wave = tid >> 6, lane = tid & 63;
  {
    const float4* s = (const float4*)w2F;
    float4* d = (float4*)wl;
#pragma unroll
    for (int i = 0; i < 18; i++) d[tid + i * 256] = s[tid + i * 256];
  }
  if (tid < 64) { lsum[tid] = 0.f; lssq[tid] = 0.f; }
  __syncthreads();
  const int m = lane & 15, q = lane >> 4;
  const bf16x8* wf = (const bf16x8*)wl;
  const f32x4 fz = {0.f, 0.f, 0.f, 0.f};
  float psum[4] = {0, 0, 0, 0}, pssq[4] = {0, 0, 0, 0};
  const bf16x8 zz = bzero8();
  for (int rt = blockIdx.x * 4 + wave; rt < n_rowtiles; rt += gridDim.x * 4) {
    const int r0 = rt * 16;
    f32x4 acc[4] = {fz, fz, fz, fz};
#pragma unroll
    for (int gk = 0; gk < 9; gk++) {
      const int idx = nbr[(size_t)(r0 + m) * 9 + gk];
      const bool valid = idx >= 0;
      const bf16x8* hp = (const bf16x8*)(h1 + (size_t)(valid ? idx : 0) * 64);
      bf16x8 x0 = hp[q], x1 = hp[4 + q];
      if (!valid) { x0 = zz; x1 = zz; }
#pragma unroll
      for (int ct = 0; ct < 4; ct++) {
        acc[ct] = mfma16(x0, wf[(gk * 8 + ct * 2 + 0) * 64 + lane], acc[ct]);
        acc[ct] = mfma16(x1, wf[(gk * 8 + ct * 2 + 1) * 64 + lane], acc[ct]);
      }
    }
#pragma unroll
    for (int ct = 0; ct < 4; ct++) {
      const int col = ct * 16 + m;
#pragma unroll
      for (int r = 0; r < 4; r++) {
        const float v = acc[ct][r];
        z2[(size_t)(r0 + q * 4 + r) * 64 + col] = (bf16_t)v;
        psum[ct] += v;
        pssq[ct] += v * v;
      }
    }
  }
#pragma unroll
  for (int ct = 0; ct < 4; ct++) {
    atomicAdd(&lsum[ct * 16 + m], psum[ct]);
    atomicAdd(&lssq[ct * 16 + m], pssq[ct]);
  }
  __syncthreads();
  if (tid < 64) {
    atomicAdd(&sum2[tid], lsum[tid]);
    atomicAdd(&ssq2[tid], lssq[tid]);
  }
}

// ---------------------------------------------------------------------------
// k4: out = (as*(fb@ws)+cs) + relu(a3*(h2@w3)+c3), f32 out (N,256).
__global__ __launch_bounds__(256) void k4_final(
    const bf16_t* __restrict__ fb, const bf16_t* __restrict__ h2,
    const bf16_t* __restrict__ wsF, const bf16_t* __restrict__ w3F,
    const float* __restrict__ as_, const float* __restrict__ cs_,
    const float* __restrict__ a3, const float* __restrict__ c3,
    float* __restrict__ out) {
  __shared__ __align__(16) bf16_t wl[2 * 16384];  // 64KB
  const int tid = threadIdx.x, wave = tid >> 6, lane = tid & 63;
  {
    const float4* s1 = (const float4*)wsF;
    const float4* s2 = (const float4*)w3F;
    float4* d = (float4*)wl;
#pragma unroll
    for (int i = 0; i < 8; i++) d[tid + i * 256] = s1[tid + i * 256];
#pragma unroll
    for (int i = 0; i < 8; i++) d[2048 + tid + i * 256] = s2[tid + i * 256];
  }
  __syncthreads();
  const int r0 = (blockIdx.x * 4 + wave) * 16;
  const int m = lane & 15, q = lane >> 4;
  const bf16x8* fv = (const bf16x8*)(fb + (size_t)r0 * 64);
  const bf16x8* hv = (const bf16x8*)(h2 + (size_t)r0 * 64);
  bf16x8 fa0 = fv[m * 8 + q], fa1 = fv[m * 8 + 4 + q];
  bf16x8 ha0 = hv[m * 8 + q], ha1 = hv[m * 8 + 4 + q];
  const bf16x8* wsf = (const bf16x8*)wl;
  const bf16x8* w3f = (const bf16x8*)(wl + 16384);
#pragma unroll
  for (int ct = 0; ct < 16; ct++) {
    f32x4 accs = {0.f, 0.f, 0.f, 0.f}, accz = {0.f, 0.f, 0.f, 0.f};
    accs = mfma16(fa0, wsf[(ct * 2 + 0) * 64 + lane], accs);
    accs = mfma16(fa1, wsf[(ct * 2 + 1) * 64 + lane], accs);
    accz = mfma16(ha0, w3f[(ct * 2 + 0) * 64 + lane], accz);
    accz = mfma16(ha1, w3f[(ct * 2 + 1) * 64 + lane], accz);
    const int col = ct * 16 + m;
    const float As = as_[col], Cs = cs_[col], Az = a3[col], Cz = c3[col];
#pragma unroll
    for (int r = 0; r < 4; r++)
      out[(size_t)(r0 + q * 4 + r) * 256 + col] =
          (As * accs[r] + Cs) + fmaxf(Az * accz[r] + Cz, 0.f);
  }
}

// ---------------------------------------------------------------------------
extern "C" void kernel_launch(void* const* d_in, const int* in_sizes, int n_in,
                              void* d_out, int out_size, void* d_ws, size_t ws_size,
                              hipStream_t stream) {
  const float* feats = (const float*)d_in[0];
  const int* nbr = (const int*)d_in[1];
  const float* w1 = (const float*)d_in[2];
  const float* g1 = (const float*)d_in[4];
  const float* be1 = (const float*)d_in[5];
  const float* w2 = (const float*)d_in[6];
  const float* g2 = (const float*)d_in[8];
  const float* be2 = (const float*)d_in[9];
  const float* w3 = (const float*)d_in[10];
  const float* g3 = (const float*)d_in[12];
  const float* be3 = (const float*)d_in[13];
  const float* ws = (const float*)d_in[14];
  const float* gs = (const float*)d_in[16];
  const float* bes = (const float*)d_in[17];
  float* out = (float*)d_out;

  char* base = (char*)d_ws;
  bf16_t* fb = (bf16_t*)(base);                    // feats bf16: 102.4 MB
  bf16_t* bufB = (bf16_t*)(base + 102400000);      // h1 (K1/K2) then h2 (K3/K4)
  bf16_t* z2 = (bf16_t*)(base + 204800000);        // 102.4 MB
  bf16_t* w1F = (bf16_t*)(base + 307200000);
  bf16_t* w2F = w1F + 4096;
  bf16_t* wsF = w2F + 36864;
  bf16_t* w3F = wsF + 16384;
  float* G = (float*)(w3F + 16384);
  float* colF = G + 4096;
  float* H = colF + 64;
  float* colH = H + 4096;
  float* sum2 = colH + 64;
  float* ssq2 = sum2 + 64;
  float* a1 = ssq2 + 64;
  float* c1 = a1 + 64;
  float* as_ = c1 + 64;
  float* cs_ = as_ + 256;
  float* a2 = cs_ + 256;
  float* c2 = a2 + 64;
  float* a3 = c2 + 64;
  float* c3 = a3 + 256;

  // zero the accumulator region (G..ssq2)
  hipMemsetAsync(G, 0, (4096 + 64 + 4096 + 64 + 64 + 64) * sizeof(float), stream);

  k_prep<<<dim3(36), dim3(256), 0, stream>>>(w1, w2, w3, ws, w1F, w2F, w3F, wsF);
  k_moments<0><<<dim3(512), dim3(256), 0, stream>>>(feats, fb, nullptr, nullptr, G, colF, 25000);
  k_stats<<<dim3(64), dim3(64), 0, stream>>>(G, colF, w1, 64, g1, be1, a1, c1);
  k_stats<<<dim3(256), dim3(64), 0, stream>>>(G, colF, ws, 256, gs, bes, as_, cs_);
  k1_h1<<<dim3(12500), dim3(256), 0, stream>>>(fb, w1F, a1, c1, bufB);
  k2_conv<<<dim3(1024), dim3(256), 0, stream>>>(bufB, nbr, w2F, z2, sum2, ssq2, 50000);
  k_stats2<<<dim3(1), dim3(64), 0, stream>>>(sum2, ssq2, g2, be2, a2, c2);
  k_moments<1><<<dim3(512), dim3(256), 0, stream>>>(z2, bufB, a2, c2, H, colH, 25000);
  k_stats<<<dim3(256), dim3(64), 0, stream>>>(H, colH, w3, 256, g3, be3, a3, c3);
  k4_final<<<dim3(12500), dim3(256), 0, stream>>>(fb, bufB, wsF, w3F, as_, cs_, a3, c3, out);
}